// Round 3
// baseline (1143.158 us; speedup 1.0000x reference)
//
#include <hip/hip_runtime.h>

// DGCNN on MI355X — round 3: scalar-weight GEMMs, 2 rows/thread.
// R2 post-mortem: VALUBusy 58%; idle = lgkm waits on the scalar weight
// stream (1:1 fma:weight-float). This round: 128-row tiles, each thread
// owns 2 rows x 32 cols -> 2:1 fma:weight-float, 2x ILP per wave.
// LDS ~68-72 KB -> 2 blocks/CU (8 waves/CU); betting ILP beats TLP here.
//   concat(a, b-a) @ W + bias = a @ (Wt-Wb) + b @ Wb + bias
//   conv2 gathers h1 with NODE ids -> only h1[0:N] rows needed
//   h2 [E,128] never materialized; g=[N,128] reuses dead A1/B1 ws region.

#define NN 100000
#define KNB 16
#define EE (NN * KNB)
#define ESTR 132   // 128+4 word stride: ds_read_b128 across 64 rows hits all banks evenly
#define HSTR 68    // 64+4 for k2's 64-wide tiles

// ---------------- K1: A1 = x@(W1t-W1b)+b1, B1 = x@W1b  ([N,16] -> [N,64] x2) ----
__global__ __launch_bounds__(256) void k1_kernel(
    const float* __restrict__ x, const float* __restrict__ W1,
    const float* __restrict__ b1, float* __restrict__ A1, float* __restrict__ B1)
{
    int gid = blockIdx.x * 256 + threadIdx.x;
    int n = gid >> 6;
    int j = gid & 63;
    const float* xr = x + n * 16;
    float acc_a = b1[j];
    float acc_b = 0.0f;
#pragma unroll
    for (int k = 0; k < 16; ++k) {
        float xv = xr[k];
        float wt = W1[k * 64 + j];
        float wb = W1[(16 + k) * 64 + j];
        acc_a = fmaf(xv, wt - wb, acc_a);
        acc_b = fmaf(xv, wb, acc_b);
    }
    A1[n * 64 + j] = acc_a;
    B1[n * 64 + j] = acc_b;
}

// ---------------- K2: 128 h1-rows per block; h1=relu(relu(A1+B1[col])@W2+b2);
//                      A3 = h1@(W3t-W3b)+b3 ; B3 = h1@W3b --------------------
__global__ __launch_bounds__(256, 2) void k2_kernel(
    const int* __restrict__ col,
    const float* __restrict__ A1, const float* __restrict__ B1,
    const float* __restrict__ W2, const float* __restrict__ b2,
    const float* __restrict__ W3, const float* __restrict__ b3,
    float* __restrict__ A3, float* __restrict__ B3)
{
    __shared__ float sh_t[128 * HSTR];   // 34.8 KB
    __shared__ float sh_h[128 * HSTR];   // 34.8 KB
    const int t = threadIdx.x;
    const int row0 = t & 63;
    const int part = t >> 6;
    const int ebase = blockIdx.x * 128;
    // phase A: sh_t[row] = relu(A1[e/16] + B1[col[e]])
#pragma unroll
    for (int rr = 0; rr < 2; ++rr) {
        int row = row0 + 64 * rr;
        int e = ebase + row;             // tail rows: reads valid (e < EE), stores guarded later
        int n = e >> 4;
        int c = col[e];
        const float* ar = A1 + (size_t)n * 64 + part * 16;
        const float* br = B1 + (size_t)c * 64 + part * 16;
        float* dr = sh_t + row * HSTR + part * 16;
#pragma unroll
        for (int i = 0; i < 16; i += 4) {
            float4 a = *(const float4*)(ar + i);
            float4 b = *(const float4*)(br + i);
            float4 r;
            r.x = fmaxf(a.x + b.x, 0.0f); r.y = fmaxf(a.y + b.y, 0.0f);
            r.z = fmaxf(a.z + b.z, 0.0f); r.w = fmaxf(a.w + b.w, 0.0f);
            *(float4*)(dr + i) = r;
        }
    }
    __syncthreads();
    const int cg = __builtin_amdgcn_readfirstlane(part);     // wave-uniform
    // phase B: h = relu(sh_t @ W2 + b2); thread: 2 rows x 16 cols (cg*16..+15)
    {
        float acc[2][16];
#pragma unroll
        for (int r = 0; r < 2; ++r)
#pragma unroll
            for (int j = 0; j < 16; ++j) acc[r][j] = 0.0f;
        const float* h0 = sh_t + row0 * HSTR;
        const float* h1 = sh_t + (row0 + 64) * HSTR;
        for (int k0 = 0; k0 < 64; k0 += 4) {
            float4 ha = *(const float4*)(h0 + k0);
            float4 hb = *(const float4*)(h1 + k0);
#pragma unroll
            for (int u = 0; u < 4; ++u) {
                float va = (u == 0) ? ha.x : (u == 1) ? ha.y : (u == 2) ? ha.z : ha.w;
                float vb = (u == 0) ? hb.x : (u == 1) ? hb.y : (u == 2) ? hb.z : hb.w;
                const float* wr = W2 + (k0 + u) * 64 + cg * 16;  // uniform -> s_load
#pragma unroll
                for (int jq = 0; jq < 4; ++jq) {
                    float4 w = *(const float4*)(wr + jq * 4);
                    acc[0][jq*4+0] = fmaf(va, w.x, acc[0][jq*4+0]);
                    acc[0][jq*4+1] = fmaf(va, w.y, acc[0][jq*4+1]);
                    acc[0][jq*4+2] = fmaf(va, w.z, acc[0][jq*4+2]);
                    acc[0][jq*4+3] = fmaf(va, w.w, acc[0][jq*4+3]);
                    acc[1][jq*4+0] = fmaf(vb, w.x, acc[1][jq*4+0]);
                    acc[1][jq*4+1] = fmaf(vb, w.y, acc[1][jq*4+1]);
                    acc[1][jq*4+2] = fmaf(vb, w.z, acc[1][jq*4+2]);
                    acc[1][jq*4+3] = fmaf(vb, w.w, acc[1][jq*4+3]);
                }
            }
        }
        const float* bp = b2 + cg * 16;                          // uniform
#pragma unroll
        for (int rr = 0; rr < 2; ++rr) {
            float* orow = sh_h + (row0 + 64 * rr) * HSTR + cg * 16;
#pragma unroll
            for (int j = 0; j < 16; j += 4) {
                float4 b = *(const float4*)(bp + j);
                float4 r;
                r.x = fmaxf(acc[rr][j+0] + b.x, 0.0f); r.y = fmaxf(acc[rr][j+1] + b.y, 0.0f);
                r.z = fmaxf(acc[rr][j+2] + b.z, 0.0f); r.w = fmaxf(acc[rr][j+3] + b.w, 0.0f);
                *(float4*)(orow + j) = r;
            }
        }
    }
    __syncthreads();
    // phase C: two k-passes (Wt then Wb), one live weight stream each
    {
        float aT[2][32], aB[2][32];
        const float* h0 = sh_h + row0 * HSTR;
        const float* h1 = sh_h + (row0 + 64) * HSTR;
#pragma unroll
        for (int r = 0; r < 2; ++r)
#pragma unroll
            for (int j = 0; j < 32; ++j) { aT[r][j] = 0.0f; aB[r][j] = 0.0f; }
        for (int k0 = 0; k0 < 64; k0 += 4) {
            float4 ha = *(const float4*)(h0 + k0);
            float4 hb = *(const float4*)(h1 + k0);
#pragma unroll
            for (int u = 0; u < 4; ++u) {
                float va = (u == 0) ? ha.x : (u == 1) ? ha.y : (u == 2) ? ha.z : ha.w;
                float vb = (u == 0) ? hb.x : (u == 1) ? hb.y : (u == 2) ? hb.z : hb.w;
                const float* wr = W3 + (k0 + u) * 128 + cg * 32;       // uniform
#pragma unroll
                for (int jq = 0; jq < 8; ++jq) {
                    float4 w = *(const float4*)(wr + jq * 4);
                    aT[0][jq*4+0] = fmaf(va, w.x, aT[0][jq*4+0]);
                    aT[0][jq*4+1] = fmaf(va, w.y, aT[0][jq*4+1]);
                    aT[0][jq*4+2] = fmaf(va, w.z, aT[0][jq*4+2]);
                    aT[0][jq*4+3] = fmaf(va, w.w, aT[0][jq*4+3]);
                    aT[1][jq*4+0] = fmaf(vb, w.x, aT[1][jq*4+0]);
                    aT[1][jq*4+1] = fmaf(vb, w.y, aT[1][jq*4+1]);
                    aT[1][jq*4+2] = fmaf(vb, w.z, aT[1][jq*4+2]);
                    aT[1][jq*4+3] = fmaf(vb, w.w, aT[1][jq*4+3]);
                }
            }
        }
        for (int k0 = 0; k0 < 64; k0 += 4) {
            float4 ha = *(const float4*)(h0 + k0);
            float4 hb = *(const float4*)(h1 + k0);
#pragma unroll
            for (int u = 0; u < 4; ++u) {
                float va = (u == 0) ? ha.x : (u == 1) ? ha.y : (u == 2) ? ha.z : ha.w;
                float vb = (u == 0) ? hb.x : (u == 1) ? hb.y : (u == 2) ? hb.z : hb.w;
                const float* wr = W3 + (64 + k0 + u) * 128 + cg * 32;  // uniform
#pragma unroll
                for (int jq = 0; jq < 8; ++jq) {
                    float4 w = *(const float4*)(wr + jq * 4);
                    aB[0][jq*4+0] = fmaf(va, w.x, aB[0][jq*4+0]);
                    aB[0][jq*4+1] = fmaf(va, w.y, aB[0][jq*4+1]);
                    aB[0][jq*4+2] = fmaf(va, w.z, aB[0][jq*4+2]);
                    aB[0][jq*4+3] = fmaf(va, w.w, aB[0][jq*4+3]);
                    aB[1][jq*4+0] = fmaf(vb, w.x, aB[1][jq*4+0]);
                    aB[1][jq*4+1] = fmaf(vb, w.y, aB[1][jq*4+1]);
                    aB[1][jq*4+2] = fmaf(vb, w.z, aB[1][jq*4+2]);
                    aB[1][jq*4+3] = fmaf(vb, w.w, aB[1][jq*4+3]);
                }
            }
        }
        const float* bp = b3 + cg * 32;                               // uniform
#pragma unroll
        for (int rr = 0; rr < 2; ++rr) {
            int e = ebase + row0 + 64 * rr;
            if (e < NN) {
                float* Ad = A3 + (size_t)e * 128 + cg * 32;
                float* Bd = B3 + (size_t)e * 128 + cg * 32;
#pragma unroll
                for (int j = 0; j < 32; j += 4) {
                    float4 b = *(const float4*)(bp + j);
                    float4 ra, rb;
                    ra.x = aT[rr][j+0] - aB[rr][j+0] + b.x;
                    ra.y = aT[rr][j+1] - aB[rr][j+1] + b.y;
                    ra.z = aT[rr][j+2] - aB[rr][j+2] + b.z;
                    ra.w = aT[rr][j+3] - aB[rr][j+3] + b.w;
                    rb.x = aB[rr][j+0]; rb.y = aB[rr][j+1];
                    rb.z = aB[rr][j+2]; rb.w = aB[rr][j+3];
                    *(float4*)(Ad + j) = ra;
                    *(float4*)(Bd + j) = rb;
                }
            }
        }
    }
}

// ---------------- K3: 8 nodes = 128 edges per block. gather->relu->@W4->max_K->g
__global__ __launch_bounds__(256, 2) void k3_kernel(
    const int* __restrict__ col,
    const float* __restrict__ A3, const float* __restrict__ B3,
    const float* __restrict__ W4, const float* __restrict__ b4,
    float* __restrict__ g)
{
    __shared__ float sh_a[1024];           // 8 nodes' A3 rows
    __shared__ float sh_e[128 * ESTR];     // 67.6 KB edge tile / raw h2
    const int t = threadIdx.x;
    const int node0 = blockIdx.x * 8;
    const int e0 = node0 * KNB;
    const int row0 = t & 63;
    const int part = t >> 6;

#pragma unroll
    for (int r = 0; r < 4; ++r)
        sh_a[t + r * 256] = A3[(size_t)node0 * 128 + t + r * 256];
    __syncthreads();

    // phase 1: sh_e[row] = relu(A3[node] + B3[col]); thread: 2 rows, 32-float slab
#pragma unroll
    for (int rr = 0; rr < 2; ++rr) {
        const int row = row0 + 64 * rr;
        const int c = col[e0 + row];
        const float* brow = B3 + (size_t)c * 128 + part * 32;
        const float* arow = sh_a + (row >> 4) * 128 + part * 32;
        float* erow = sh_e + row * ESTR + part * 32;
#pragma unroll
        for (int i = 0; i < 32; i += 4) {
            float4 bv = *(const float4*)(brow + i);
            float4 av = *(const float4*)(arow + i);
            float4 r;
            r.x = fmaxf(av.x + bv.x, 0.0f); r.y = fmaxf(av.y + bv.y, 0.0f);
            r.z = fmaxf(av.z + bv.z, 0.0f); r.w = fmaxf(av.w + bv.w, 0.0f);
            *(float4*)(erow + i) = r;
        }
    }
    __syncthreads();

    // phase 2: raw h2 for 2 rows x 32 cols (cg*32..+31)
    const int cg = __builtin_amdgcn_readfirstlane(part);
    float acc[2][32];
#pragma unroll
    for (int r = 0; r < 2; ++r)
#pragma unroll
        for (int j = 0; j < 32; ++j) acc[r][j] = 0.0f;
    {
        const float* h0 = sh_e + row0 * ESTR;
        const float* h1 = sh_e + (row0 + 64) * ESTR;
        const float* wbase = W4 + cg * 32;
        for (int k0 = 0; k0 < 128; k0 += 4) {
            float4 ha = *(const float4*)(h0 + k0);
            float4 hb = *(const float4*)(h1 + k0);
#pragma unroll
            for (int u = 0; u < 4; ++u) {
                float va = (u == 0) ? ha.x : (u == 1) ? ha.y : (u == 2) ? ha.z : ha.w;
                float vb = (u == 0) ? hb.x : (u == 1) ? hb.y : (u == 2) ? hb.z : hb.w;
                const float* wr = wbase + (k0 + u) * 128;        // uniform -> s_load
#pragma unroll
                for (int jq = 0; jq < 8; ++jq) {
                    float4 w = *(const float4*)(wr + jq * 4);
                    acc[0][jq*4+0] = fmaf(va, w.x, acc[0][jq*4+0]);
                    acc[0][jq*4+1] = fmaf(va, w.y, acc[0][jq*4+1]);
                    acc[0][jq*4+2] = fmaf(va, w.z, acc[0][jq*4+2]);
                    acc[0][jq*4+3] = fmaf(va, w.w, acc[0][jq*4+3]);
                    acc[1][jq*4+0] = fmaf(vb, w.x, acc[1][jq*4+0]);
                    acc[1][jq*4+1] = fmaf(vb, w.y, acc[1][jq*4+1]);
                    acc[1][jq*4+2] = fmaf(vb, w.z, acc[1][jq*4+2]);
                    acc[1][jq*4+3] = fmaf(vb, w.w, acc[1][jq*4+3]);
                }
            }
        }
    }
    __syncthreads();                        // all reads of sh_e done
#pragma unroll
    for (int rr = 0; rr < 2; ++rr) {
        float* orow = sh_e + (row0 + 64 * rr) * ESTR + cg * 32;
#pragma unroll
        for (int j = 0; j < 32; j += 4)
            *(float4*)(orow + j) = make_float4(acc[rr][j], acc[rr][j+1],
                                               acc[rr][j+2], acc[rr][j+3]);
    }
    __syncthreads();

    // phase 3: g[node] = relu(max_16(raw) + b4); 4 outputs/thread
#pragma unroll
    for (int r = 0; r < 4; ++r) {
        int idx = t + r * 256;              // 0..1023
        int ni = idx >> 7, j = idx & 127;
        const float* base = sh_e + (ni * 16) * ESTR + j;
        float m = base[0];
#pragma unroll
        for (int rr2 = 1; rr2 < 16; ++rr2) m = fmaxf(m, base[rr2 * ESTR]);
        g[(size_t)(node0 + ni) * 128 + j] = fmaxf(m + b4[j], 0.0f);
    }
}

// ---------------- K4: 128 nodes/block; out = relu(g@W5+b5) @ W6 + b6 ----------
__global__ __launch_bounds__(256, 2) void k4_kernel(
    const float* __restrict__ g,
    const float* __restrict__ W5, const float* __restrict__ b5,
    const float* __restrict__ W6, const float* __restrict__ b6,
    float* __restrict__ out)
{
    __shared__ float sh[128 * ESTR];        // 67.6 KB: g tile, then t1 tile
    const int t = threadIdx.x;
    const int n0 = blockIdx.x * 128;
    const int row0 = t & 63;
    const int part = t >> 6;

#pragma unroll
    for (int rr = 0; rr < 2; ++rr) {        // stage g (clamp tail reads)
        int row = row0 + 64 * rr;
        int gn = n0 + row; if (gn >= NN) gn = NN - 1;
        const float* grow = g + (size_t)gn * 128 + part * 32;
        float* dst = sh + row * ESTR + part * 32;
#pragma unroll
        for (int i = 0; i < 32; i += 4)
            *(float4*)(dst + i) = *(const float4*)(grow + i);
    }
    __syncthreads();

    const int cg = __builtin_amdgcn_readfirstlane(part);
    float acc[2][32];
#pragma unroll
    for (int r = 0; r < 2; ++r)
#pragma unroll
        for (int j = 0; j < 32; ++j) acc[r][j] = 0.0f;
    {   // t1 = g @ W5 (pre-bias), 2 rows x 32 cols
        const float* h0 = sh + row0 * ESTR;
        const float* h1 = sh + (row0 + 64) * ESTR;
        const float* wbase = W5 + cg * 32;
        for (int k0 = 0; k0 < 128; k0 += 4) {
            float4 ha = *(const float4*)(h0 + k0);
            float4 hb = *(const float4*)(h1 + k0);
#pragma unroll
            for (int u = 0; u < 4; ++u) {
                float va = (u == 0) ? ha.x : (u == 1) ? ha.y : (u == 2) ? ha.z : ha.w;
                float vb = (u == 0) ? hb.x : (u == 1) ? hb.y : (u == 2) ? hb.z : hb.w;
                const float* wr = wbase + (k0 + u) * 128;        // uniform
#pragma unroll
                for (int jq = 0; jq < 8; ++jq) {
                    float4 w = *(const float4*)(wr + jq * 4);
                    acc[0][jq*4+0] = fmaf(va, w.x, acc[0][jq*4+0]);
                    acc[0][jq*4+1] = fmaf(va, w.y, acc[0][jq*4+1]);
                    acc[0][jq*4+2] = fmaf(va, w.z, acc[0][jq*4+2]);
                    acc[0][jq*4+3] = fmaf(va, w.w, acc[0][jq*4+3]);
                    acc[1][jq*4+0] = fmaf(vb, w.x, acc[1][jq*4+0]);
                    acc[1][jq*4+1] = fmaf(vb, w.y, acc[1][jq*4+1]);
                    acc[1][jq*4+2] = fmaf(vb, w.z, acc[1][jq*4+2]);
                    acc[1][jq*4+3] = fmaf(vb, w.w, acc[1][jq*4+3]);
                }
            }
        }
    }
    __syncthreads();                        // g reads done; overwrite with t1
    {
        const float* bp = b5 + cg * 32;                          // uniform
#pragma unroll
        for (int rr = 0; rr < 2; ++rr) {
            float* orow = sh + (row0 + 64 * rr) * ESTR + cg * 32;
#pragma unroll
            for (int j = 0; j < 32; j += 4) {
                float4 b = *(const float4*)(bp + j);
                float4 r;
                r.x = fmaxf(acc[rr][j+0] + b.x, 0.0f);
                r.y = fmaxf(acc[rr][j+1] + b.y, 0.0f);
                r.z = fmaxf(acc[rr][j+2] + b.z, 0.0f);
                r.w = fmaxf(acc[rr][j+3] + b.w, 0.0f);
                *(float4*)(orow + j) = r;
            }
        }
    }
    __syncthreads();
    {   // out = t1 @ W6 + b6; thread: 2 nodes x 10 cols (jb uniform)
        const int jb = cg * 10;
#pragma unroll
        for (int rr = 0; rr < 2; ++rr) {
            int gn = n0 + row0 + 64 * rr;
            float acc6[10];
#pragma unroll
            for (int j = 0; j < 10; ++j) acc6[j] = 0.0f;
            const float* trow = sh + (row0 + 64 * rr) * ESTR;
            for (int k0 = 0; k0 < 128; k0 += 4) {
                float4 h4 = *(const float4*)(trow + k0);
#pragma unroll
                for (int u = 0; u < 4; ++u) {
                    float hv = (u == 0) ? h4.x : (u == 1) ? h4.y : (u == 2) ? h4.z : h4.w;
                    const float* wr = W6 + (size_t)(k0 + u) * 40 + jb;   // uniform
#pragma unroll
                    for (int j = 0; j < 10; ++j)
                        acc6[j] = fmaf(hv, wr[j], acc6[j]);
                }
            }
            if (gn < NN) {
                const float* bp = b6 + jb;                       // uniform
                float* od = out + (size_t)gn * 40 + jb;
#pragma unroll
                for (int j = 0; j < 10; ++j) od[j] = acc6[j] + bp[j];
            }
        }
    }
}

extern "C" void kernel_launch(void* const* d_in, const int* in_sizes, int n_in,
                              void* d_out, int out_size, void* d_ws, size_t ws_size,
                              hipStream_t stream)
{
    const float* x  = (const float*)d_in[0];
    const int* ei   = (const int*)d_in[1];
    const int* col  = ei + EE;              // edge_index[1,:]
    const float* W1 = (const float*)d_in[2];
    const float* b1 = (const float*)d_in[3];
    const float* W2 = (const float*)d_in[4];
    const float* b2 = (const float*)d_in[5];
    const float* W3 = (const float*)d_in[6];
    const float* b3 = (const float*)d_in[7];
    const float* W4 = (const float*)d_in[8];
    const float* b4 = (const float*)d_in[9];
    const float* W5 = (const float*)d_in[10];
    const float* b5 = (const float*)d_in[11];
    const float* W6 = (const float*)d_in[12];
    const float* b6 = (const float*)d_in[13];
    float* out = (float*)d_out;

    float* A1 = (float*)d_ws;                    // [N,64]
    float* B1 = A1 + (size_t)NN * 64;            // [N,64]
    float* A3 = B1 + (size_t)NN * 64;            // [N,128]
    float* B3 = A3 + (size_t)NN * 128;           // [N,128]
    float* g  = A1;                              // [N,128] reuses A1+B1 (dead after k2)

    k1_kernel<<<NN * 64 / 256, 256, 0, stream>>>(x, W1, b1, A1, B1);
    k2_kernel<<<(NN + 127) / 128, 256, 0, stream>>>(col, A1, B1, W2, b2, W3, b3, A3, B3);
    k3_kernel<<<NN / 8, 256, 0, stream>>>(col, A3, B3, W4, b4, g);
    k4_kernel<<<(NN + 127) / 128, 256, 0, stream>>>(g, W5, b5, W6, b6, out);
}

// Round 4
// 601.911 us; speedup vs baseline: 1.8992x; 1.8992x over previous
//
#include <hip/hip_runtime.h>

// DGCNN on MI355X — round 4: k3 via bf16-split MFMA (3-product fp32 emulation).
// R2 structure for k1/k2/k4 (4 blocks/CU sweet spot, R3's 2-block ILP variant
// regressed). k3: h2-GEMM done as Ah*Bh + Ah*Bl + Al*Bh with
// mfma_f32_16x16x32_bf16; dropped Al*Bl term ~2^-18 rel. K-max folded
// in-register via shfl_xor over the C/D quad layout (no h2 LDS round trip).
//   concat(a, b-a) @ W + bias = a @ (Wt-Wb) + b @ Wb + bias
//   conv2 gathers h1 with NODE ids -> only h1[0:N] rows needed

#define NN 100000
#define KNB 16
#define EE (NN * KNB)
#define HSTR 68    // 64+4 for k2's 64-wide tiles
#define ESTR 132   // 128+4 for k4 tiles

typedef float floatx4 __attribute__((ext_vector_type(4)));
typedef __bf16 bf16x8 __attribute__((ext_vector_type(8)));

static __device__ __forceinline__ unsigned f2bf_rne_u(float f) {
    unsigned u = __float_as_uint(f);
    return (u + 0x7FFFu + ((u >> 16) & 1u)) >> 16;
}
static __device__ __forceinline__ float bfu2f(unsigned h) {
    return __uint_as_float(h << 16);
}

// ---------------- K1: A1 = x@(W1t-W1b)+b1, B1 = x@W1b ----------------
__global__ __launch_bounds__(256) void k1_kernel(
    const float* __restrict__ x, const float* __restrict__ W1,
    const float* __restrict__ b1, float* __restrict__ A1, float* __restrict__ B1)
{
    int gid = blockIdx.x * 256 + threadIdx.x;
    int n = gid >> 6;
    int j = gid & 63;
    const float* xr = x + n * 16;
    float acc_a = b1[j];
    float acc_b = 0.0f;
#pragma unroll
    for (int k = 0; k < 16; ++k) {
        float xv = xr[k];
        float wt = W1[k * 64 + j];
        float wb = W1[(16 + k) * 64 + j];
        acc_a = fmaf(xv, wt - wb, acc_a);
        acc_b = fmaf(xv, wb, acc_b);
    }
    A1[n * 64 + j] = acc_a;
    B1[n * 64 + j] = acc_b;
}

// ---------------- K2 (R2 version): 64 rows/block, scalar-weight GEMMs ---------
__global__ __launch_bounds__(256) void k2_kernel(
    const int* __restrict__ col,
    const float* __restrict__ A1, const float* __restrict__ B1,
    const float* __restrict__ W2, const float* __restrict__ b2,
    const float* __restrict__ W3, const float* __restrict__ b3,
    float* __restrict__ A3, float* __restrict__ B3)
{
    __shared__ float sh_t[64 * HSTR];
    __shared__ float sh_h[64 * HSTR];
    const int t = threadIdx.x;
    const int row = t & 63;
    const int part = t >> 6;
    const int e = blockIdx.x * 64 + row;
    {
        int n = e >> 4;
        int c = col[e];
        const float* ar = A1 + (size_t)n * 64 + part * 16;
        const float* br = B1 + (size_t)c * 64 + part * 16;
        float* dr = sh_t + row * HSTR + part * 16;
#pragma unroll
        for (int i = 0; i < 16; i += 4) {
            float4 a = *(const float4*)(ar + i);
            float4 b = *(const float4*)(br + i);
            float4 r;
            r.x = fmaxf(a.x + b.x, 0.0f); r.y = fmaxf(a.y + b.y, 0.0f);
            r.z = fmaxf(a.z + b.z, 0.0f); r.w = fmaxf(a.w + b.w, 0.0f);
            *(float4*)(dr + i) = r;
        }
    }
    __syncthreads();
    const int cg = __builtin_amdgcn_readfirstlane(part);
    {
        float acc[16];
#pragma unroll
        for (int j = 0; j < 16; ++j) acc[j] = 0.0f;
        const float* hr = sh_t + row * HSTR;
        for (int k0 = 0; k0 < 64; k0 += 4) {
            float4 h4 = *(const float4*)(hr + k0);
#pragma unroll
            for (int u = 0; u < 4; ++u) {
                float hv = (u == 0) ? h4.x : (u == 1) ? h4.y : (u == 2) ? h4.z : h4.w;
                const float* wr = W2 + (k0 + u) * 64 + cg * 16;
#pragma unroll
                for (int jq = 0; jq < 4; ++jq) {
                    float4 w = *(const float4*)(wr + jq * 4);
                    acc[jq*4+0] = fmaf(hv, w.x, acc[jq*4+0]);
                    acc[jq*4+1] = fmaf(hv, w.y, acc[jq*4+1]);
                    acc[jq*4+2] = fmaf(hv, w.z, acc[jq*4+2]);
                    acc[jq*4+3] = fmaf(hv, w.w, acc[jq*4+3]);
                }
            }
        }
        const float* bp = b2 + cg * 16;
        float* orow = sh_h + row * HSTR + cg * 16;
#pragma unroll
        for (int j = 0; j < 16; j += 4) {
            float4 b = *(const float4*)(bp + j);
            float4 r;
            r.x = fmaxf(acc[j+0] + b.x, 0.0f); r.y = fmaxf(acc[j+1] + b.y, 0.0f);
            r.z = fmaxf(acc[j+2] + b.z, 0.0f); r.w = fmaxf(acc[j+3] + b.w, 0.0f);
            *(float4*)(orow + j) = r;
        }
    }
    __syncthreads();
    {
        float aT[32], aB[32];
#pragma unroll
        for (int j = 0; j < 32; ++j) { aT[j] = 0.0f; aB[j] = 0.0f; }
        const float* hr = sh_h + row * HSTR;
        for (int k0 = 0; k0 < 64; k0 += 4) {
            float4 h4 = *(const float4*)(hr + k0);
#pragma unroll
            for (int u = 0; u < 4; ++u) {
                float hv = (u == 0) ? h4.x : (u == 1) ? h4.y : (u == 2) ? h4.z : h4.w;
                const float* wt = W3 + (k0 + u) * 128 + cg * 32;
                const float* wb = W3 + (64 + k0 + u) * 128 + cg * 32;
#pragma unroll
                for (int jq = 0; jq < 8; ++jq) {
                    float4 w0 = *(const float4*)(wt + jq * 4);
                    float4 w1 = *(const float4*)(wb + jq * 4);
                    aT[jq*4+0] = fmaf(hv, w0.x, aT[jq*4+0]);
                    aT[jq*4+1] = fmaf(hv, w0.y, aT[jq*4+1]);
                    aT[jq*4+2] = fmaf(hv, w0.z, aT[jq*4+2]);
                    aT[jq*4+3] = fmaf(hv, w0.w, aT[jq*4+3]);
                    aB[jq*4+0] = fmaf(hv, w1.x, aB[jq*4+0]);
                    aB[jq*4+1] = fmaf(hv, w1.y, aB[jq*4+1]);
                    aB[jq*4+2] = fmaf(hv, w1.z, aB[jq*4+2]);
                    aB[jq*4+3] = fmaf(hv, w1.w, aB[jq*4+3]);
                }
            }
        }
        if (e < NN) {
            const float* bp = b3 + cg * 32;
            float* Ad = A3 + (size_t)e * 128 + cg * 32;
            float* Bd = B3 + (size_t)e * 128 + cg * 32;
#pragma unroll
            for (int j = 0; j < 32; j += 4) {
                float4 b = *(const float4*)(bp + j);
                float4 ra, rb;
                ra.x = aT[j+0] - aB[j+0] + b.x; ra.y = aT[j+1] - aB[j+1] + b.y;
                ra.z = aT[j+2] - aB[j+2] + b.z; ra.w = aT[j+3] - aB[j+3] + b.w;
                rb.x = aB[j+0]; rb.y = aB[j+1]; rb.z = aB[j+2]; rb.w = aB[j+3];
                *(float4*)(Ad + j) = ra;
                *(float4*)(Bd + j) = rb;
            }
        }
    }
}

// ---------------- KW: split W4 into bf16 hi/lo, B-fragment order --------------
// Frag (kc,nt): lane l holds W[kc*32 + (l>>4)*8 + j][nt*16 + (l&15)], j=0..7.
// Stored at ushort index ((kc*8+nt)*64 + l)*8 + j.
__global__ __launch_bounds__(256) void kw_kernel(
    const float* __restrict__ W4,
    unsigned short* __restrict__ WH, unsigned short* __restrict__ WL)
{
    int d = blockIdx.x * 256 + threadIdx.x;   // 0..2047 = (kc,nt,lane)
    int c  = d & 15;
    int q  = (d >> 4) & 3;
    int nt = (d >> 6) & 7;
    int kc = d >> 9;
    int n = nt * 16 + c;
    int kbase = kc * 32 + q * 8;
    unsigned hs[8], ls[8];
#pragma unroll
    for (int j = 0; j < 8; ++j) {
        float f = W4[(size_t)(kbase + j) * 128 + n];
        unsigned h = f2bf_rne_u(f);
        float r = f - bfu2f(h);           // exact residual
        hs[j] = h;
        ls[j] = f2bf_rne_u(r);
    }
    uint4 H, L;
    H.x = hs[0] | (hs[1] << 16); H.y = hs[2] | (hs[3] << 16);
    H.z = hs[4] | (hs[5] << 16); H.w = hs[6] | (hs[7] << 16);
    L.x = ls[0] | (ls[1] << 16); L.y = ls[2] | (ls[3] << 16);
    L.z = ls[4] | (ls[5] << 16); L.w = ls[6] | (ls[7] << 16);
    *(uint4*)(WH + (size_t)d * 8) = H;
    *(uint4*)(WL + (size_t)d * 8) = L;
}

// ---------------- K3: MFMA. Block = 4 nodes = 64 edges, 256 thr. --------------
// A-tile (64x128) split hi/lo in LDS, fragment order: frag (mt,kc) is 1 KB
// contiguous, lane l's 16B at ((mt*4+kc)*512 + l*8) ushorts.
__global__ __launch_bounds__(256) void k3_kernel(
    const int* __restrict__ col,
    const float* __restrict__ A3, const float* __restrict__ B3,
    const unsigned short* __restrict__ WH, const unsigned short* __restrict__ WL,
    const float* __restrict__ b4, float* __restrict__ g)
{
    __shared__ float sh_a[512];
    __shared__ __align__(16) unsigned short aHi[8192];   // 16 KB
    __shared__ __align__(16) unsigned short aLo[8192];   // 16 KB
    const int t = threadIdx.x;
    const int node0 = blockIdx.x * 4;
    const int e0 = node0 * KNB;
    const int row = t & 63;
    const int kcm = t >> 6;          // this thread's k-chunk in phase 1

    sh_a[t]       = A3[(size_t)node0 * 128 + t];
    sh_a[t + 256] = A3[(size_t)node0 * 128 + t + 256];
    __syncthreads();

    // phase 1: gather+relu+split 32 values (cols kcm*32..+31) of edge `row`
    {
        const int c = col[e0 + row];
        const int mt = row >> 4, m = row & 15;
        const float* brow = B3 + (size_t)c * 128 + kcm * 32;
        const float* arow = sh_a + mt * 128 + kcm * 32;
        const int base = (mt * 4 + kcm) * 512 + m * 8;
#pragma unroll
        for (int q = 0; q < 4; ++q) {
            unsigned hs[8], ls[8];
#pragma unroll
            for (int i = 0; i < 8; i += 4) {
                float4 bv = *(const float4*)(brow + q * 8 + i);
                float4 av = *(const float4*)(arow + q * 8 + i);
                float vv[4];
                vv[0] = fmaxf(av.x + bv.x, 0.0f); vv[1] = fmaxf(av.y + bv.y, 0.0f);
                vv[2] = fmaxf(av.z + bv.z, 0.0f); vv[3] = fmaxf(av.w + bv.w, 0.0f);
#pragma unroll
                for (int u = 0; u < 4; ++u) {
                    unsigned h = f2bf_rne_u(vv[u]);
                    float r = vv[u] - bfu2f(h);
                    hs[i + u] = h;
                    ls[i + u] = f2bf_rne_u(r);
                }
            }
            uint4 H, L;
            H.x = hs[0] | (hs[1] << 16); H.y = hs[2] | (hs[3] << 16);
            H.z = hs[4] | (hs[5] << 16); H.w = hs[6] | (hs[7] << 16);
            L.x = ls[0] | (ls[1] << 16); L.y = ls[2] | (ls[3] << 16);
            L.z = ls[4] | (ls[5] << 16); L.w = ls[6] | (ls[7] << 16);
            *(uint4*)(aHi + base + q * 128) = H;
            *(uint4*)(aLo + base + q * 128) = L;
        }
    }
    __syncthreads();

    // phase 2: wave wv owns n-tiles {wv*2, wv*2+1} x all 4 m-tiles
    const int wv = t >> 6;
    const int lane = t & 63;
    const int ntb = wv * 2;
    floatx4 acc[4][2];
#pragma unroll
    for (int mt = 0; mt < 4; ++mt)
#pragma unroll
        for (int ntl = 0; ntl < 2; ++ntl)
            acc[mt][ntl] = (floatx4){0.0f, 0.0f, 0.0f, 0.0f};

    for (int kc = 0; kc < 4; ++kc) {
        bf16x8 bh[2], bl[2];
#pragma unroll
        for (int ntl = 0; ntl < 2; ++ntl) {
            int nt = ntb + ntl;
            bh[ntl] = __builtin_bit_cast(bf16x8,
                *(const uint4*)(WH + (size_t)((kc * 8 + nt) * 64 + lane) * 8));
            bl[ntl] = __builtin_bit_cast(bf16x8,
                *(const uint4*)(WL + (size_t)((kc * 8 + nt) * 64 + lane) * 8));
        }
        bf16x8 ah[4], al[4];
#pragma unroll
        for (int mt = 0; mt < 4; ++mt) {
            ah[mt] = __builtin_bit_cast(bf16x8,
                *(const uint4*)(aHi + (mt * 4 + kc) * 512 + lane * 8));
            al[mt] = __builtin_bit_cast(bf16x8,
                *(const uint4*)(aLo + (mt * 4 + kc) * 512 + lane * 8));
        }
#pragma unroll
        for (int mt = 0; mt < 4; ++mt)
#pragma unroll
            for (int ntl = 0; ntl < 2; ++ntl) {
                acc[mt][ntl] = __builtin_amdgcn_mfma_f32_16x16x32_bf16(
                    ah[mt], bh[ntl], acc[mt][ntl], 0, 0, 0);
                acc[mt][ntl] = __builtin_amdgcn_mfma_f32_16x16x32_bf16(
                    ah[mt], bl[ntl], acc[mt][ntl], 0, 0, 0);
                acc[mt][ntl] = __builtin_amdgcn_mfma_f32_16x16x32_bf16(
                    al[mt], bh[ntl], acc[mt][ntl], 0, 0, 0);
            }
    }

    // phase 3: K-max in-register. D layout: row=(lane>>4)*4+reg, col=lane&15.
    // m-tile mt == node node0+mt (16 edges of one node = one m-tile).
#pragma unroll
    for (int mt = 0; mt < 4; ++mt)
#pragma unroll
        for (int ntl = 0; ntl < 2; ++ntl) {
            floatx4 a = acc[mt][ntl];
            float mm = fmaxf(fmaxf(a[0], a[1]), fmaxf(a[2], a[3]));
            mm = fmaxf(mm, __shfl_xor(mm, 16));
            mm = fmaxf(mm, __shfl_xor(mm, 32));
            if (lane < 16) {
                int ccol = (ntb + ntl) * 16 + lane;
                g[(size_t)(node0 + mt) * 128 + ccol] =
                    fmaxf(mm + b4[ccol], 0.0f);
            }
        }
}

// ---------------- K4 (R2 version): out = relu(g@W5+b5) @ W6 + b6 --------------
__global__ __launch_bounds__(256) void k4_kernel(
    const float* __restrict__ g,
    const float* __restrict__ W5, const float* __restrict__ b5,
    const float* __restrict__ W6, const float* __restrict__ b6,
    float* __restrict__ out)
{
    __shared__ float sh_g[64 * ESTR];
    __shared__ float sh_t[64 * ESTR];
    const int t = threadIdx.x;
    const int n0 = blockIdx.x * 64;
    const int row = t & 63;
    const int part = t >> 6;

    {
        int gn = n0 + row; if (gn >= NN) gn = NN - 1;
        const float* grow = g + (size_t)gn * 128 + part * 32;
        float* dst = sh_g + row * ESTR + part * 32;
#pragma unroll
        for (int i = 0; i < 32; i += 4)
            *(float4*)(dst + i) = *(const float4*)(grow + i);
    }
    __syncthreads();

    const int cg = __builtin_amdgcn_readfirstlane(part);
    {
        float acc[32];
#pragma unroll
        for (int j = 0; j < 32; ++j) acc[j] = 0.0f;
        const float* hrow = sh_g + row * ESTR;
        const float* wbase = W5 + cg * 32;
        for (int k0 = 0; k0 < 128; k0 += 4) {
            float4 h4 = *(const float4*)(hrow + k0);
#pragma unroll
            for (int u = 0; u < 4; ++u) {
                float hv = (u == 0) ? h4.x : (u == 1) ? h4.y : (u == 2) ? h4.z : h4.w;
                const float* wr = wbase + (k0 + u) * 128;
#pragma unroll
                for (int jq = 0; jq < 8; ++jq) {
                    float4 w = *(const float4*)(wr + jq * 4);
                    acc[jq*4+0] = fmaf(hv, w.x, acc[jq*4+0]);
                    acc[jq*4+1] = fmaf(hv, w.y, acc[jq*4+1]);
                    acc[jq*4+2] = fmaf(hv, w.z, acc[jq*4+2]);
                    acc[jq*4+3] = fmaf(hv, w.w, acc[jq*4+3]);
                }
            }
        }
        const float* bp = b5 + cg * 32;
        float* orow = sh_t + row * ESTR + cg * 32;
#pragma unroll
        for (int j = 0; j < 32; j += 4) {
            float4 b = *(const float4*)(bp + j);
            float4 r;
            r.x = fmaxf(acc[j+0] + b.x, 0.0f); r.y = fmaxf(acc[j+1] + b.y, 0.0f);
            r.z = fmaxf(acc[j+2] + b.z, 0.0f); r.w = fmaxf(acc[j+3] + b.w, 0.0f);
            *(float4*)(orow + j) = r;
        }
    }
    __syncthreads();
    {
        const int jb = cg * 10;
        float acc6[10];
#pragma unroll
        for (int j = 0; j < 10; ++j) acc6[j] = 0.0f;
        const float* trow = sh_t + row * ESTR;
        for (int k0 = 0; k0 < 128; k0 += 4) {
            float4 h4 = *(const float4*)(trow + k0);
#pragma unroll
            for (int u = 0; u < 4; ++u) {
                float hv = (u == 0) ? h4.x : (u == 1) ? h4.y : (u == 2) ? h4.z : h4.w;
                const float* wr = W6 + (size_t)(k0 + u) * 40 + jb;
#pragma unroll
                for (int j = 0; j < 10; ++j)
                    acc6[j] = fmaf(hv, wr[j], acc6[j]);
            }
        }
        int gn = n0 + row;
        if (gn < NN) {
            const float* bp = b6 + jb;
            float* od = out + (size_t)gn * 40 + jb;
#pragma unroll
            for (int j = 0; j < 10; ++j) od[j] = acc6[j] + bp[j];
        }
    }
}

extern "C" void kernel_launch(void* const* d_in, const int* in_sizes, int n_in,
                              void* d_out, int out_size, void* d_ws, size_t ws_size,
                              hipStream_t stream)
{
    const float* x  = (const float*)d_in[0];
    const int* ei   = (const int*)d_in[1];
    const int* col  = ei + EE;
    const float* W1 = (const float*)d_in[2];
    const float* b1 = (const float*)d_in[3];
    const float* W2 = (const float*)d_in[4];
    const float* b2 = (const float*)d_in[5];
    const float* W3 = (const float*)d_in[6];
    const float* b3 = (const float*)d_in[7];
    const float* W4 = (const float*)d_in[8];
    const float* b4 = (const float*)d_in[9];
    const float* W5 = (const float*)d_in[10];
    const float* b5 = (const float*)d_in[11];
    const float* W6 = (const float*)d_in[12];
    const float* b6 = (const float*)d_in[13];
    float* out = (float*)d_out;

    float* A1 = (float*)d_ws;                    // [N,64]
    float* B1 = A1 + (size_t)NN * 64;            // [N,64]
    float* A3 = B1 + (size_t)NN * 64;            // [N,128]
    float* B3 = A3 + (size_t)NN * 128;           // [N,128]
    unsigned short* WH = (unsigned short*)(B3 + (size_t)NN * 128);  // [16384]
    unsigned short* WL = WH + 16384;                                // [16384]
    float* g  = A1;                              // [N,128] reuses A1/B1 (dead after k2)

    kw_kernel<<<8, 256, 0, stream>>>(W4, WH, WL);
    k1_kernel<<<NN * 64 / 256, 256, 0, stream>>>(x, W1, b1, A1, B1);
    k2_kernel<<<(NN + 63) / 64, 256, 0, stream>>>(col, A1, B1, W2, b2, W3, b3, A3, B3);
    k3_kernel<<<NN / 4, 256, 0, stream>>>(col, A3, B3, WH, WL, b4, g);
    k4_kernel<<<(NN + 63) / 64, 256, 0, stream>>>(g, W5, b5, W6, b6, out);
}

// Round 5
// 477.567 us; speedup vs baseline: 2.3937x; 1.2604x over previous
//
#include <hip/hip_runtime.h>

// DGCNN on MI355X — round 5: all big GEMMs on MFMA via 3-product bf16 split.
// R4 proved the split exact enough (absmax unchanged). This round: k2/k4 use
// the same scheme with (a) frag-contiguous fp32 LDS tiles (lane*32B reads,
// 2-way alias = free), (b) wave==m-tile so GEMM1->GEMM2 handoff is
// wave-local (no barrier), (c) all weights pre-split once by kw into
// frag-ordered bf16 hi/lo. k3 unchanged from R4 (isolate the experiment).
//   concat(a, b-a) @ W + bias = a @ (Wt-Wb) + b @ Wb + bias
//   conv2 gathers h1 with NODE ids -> only h1[0:N] rows needed

#define NN 100000
#define KNB 16
#define EE (NN * KNB)

// weight fragment bases (units of 512 ushorts = one 64-lane x 8-bf16 frag)
#define W2F 0     // W2  [64][64]   : 2 kc x 4 nt  = 8
#define W3F 8     // W3X [64][256]  : 2 kc x 16 nt = 32  (cols 0-127: W3t-W3b, 128-255: W3b)
#define W4F 40    // W4  [128][128] : 4 kc x 8 nt  = 32
#define W5F 72    // W5  [128][128] : 4 kc x 8 nt  = 32
#define W6F 104   // W6  [128][48p] : 4 kc x 3 nt  = 12
#define NFRAG 116

typedef float floatx4 __attribute__((ext_vector_type(4)));
typedef __bf16 bf16x8 __attribute__((ext_vector_type(8)));

static __device__ __forceinline__ unsigned f2bf_rne_u(float f) {
    unsigned u = __float_as_uint(f);
    return (u + 0x7FFFu + ((u >> 16) & 1u)) >> 16;
}
static __device__ __forceinline__ unsigned rne16(unsigned u) {
    return (u + 0x7FFFu + ((u >> 16) & 1u)) & 0xFFFF0000u;
}
static __device__ __forceinline__ float bfu2f(unsigned h) {
    return __uint_as_float(h << 16);
}

// split 8 fp32 -> packed bf16 hi + bf16 lo (RNE both; residual exact in fp32)
static __device__ __forceinline__ void split8(float4 f0, float4 f1,
                                              bf16x8& ah, bf16x8& al) {
    float v[8] = {f0.x, f0.y, f0.z, f0.w, f1.x, f1.y, f1.z, f1.w};
    unsigned hd[4], ld[4];
#pragma unroll
    for (int p = 0; p < 4; ++p) {
        unsigned u0 = __float_as_uint(v[2 * p]);
        unsigned u1 = __float_as_uint(v[2 * p + 1]);
        unsigned h0 = rne16(u0), h1 = rne16(u1);
        float l0 = v[2 * p] - __uint_as_float(h0);
        float l1 = v[2 * p + 1] - __uint_as_float(h1);
        unsigned lu0 = rne16(__float_as_uint(l0));
        unsigned lu1 = rne16(__float_as_uint(l1));
        hd[p] = (h0 >> 16) | h1;
        ld[p] = (lu0 >> 16) | lu1;
    }
    uint4 H = {hd[0], hd[1], hd[2], hd[3]};
    uint4 L = {ld[0], ld[1], ld[2], ld[3]};
    ah = __builtin_bit_cast(bf16x8, H);
    al = __builtin_bit_cast(bf16x8, L);
}

// ---------------- KW: pre-split all weights into frag-ordered bf16 hi/lo ------
// Frag (kc,nt): lane l holds W[kc*32 + (l>>4)*8 + j][nt*16 + (l&15)], j=0..7.
__global__ __launch_bounds__(256) void kw_kernel(
    const float* __restrict__ W2, const float* __restrict__ W3,
    const float* __restrict__ W4, const float* __restrict__ W5,
    const float* __restrict__ W6,
    unsigned short* __restrict__ WH, unsigned short* __restrict__ WL)
{
    int d = blockIdx.x * 256 + threadIdx.x;
    if (d >= NFRAG * 64) return;
    int f = d >> 6, l = d & 63, c = l & 15, q = l >> 4;
    float v[8];
    if (f < W3F) {                    // W2 [64][64]
        int fx = f - W2F, kc = fx >> 2, nt = fx & 3;
        int k0 = kc * 32 + q * 8, n = nt * 16 + c;
#pragma unroll
        for (int j = 0; j < 8; ++j) v[j] = W2[(k0 + j) * 64 + n];
    } else if (f < W4F) {             // W3X [64][256]
        int fx = f - W3F, kc = fx >> 4, nt = fx & 15;
        int k0 = kc * 32 + q * 8, n = nt * 16 + c;
#pragma unroll
        for (int j = 0; j < 8; ++j) {
            int k = k0 + j;
            v[j] = (n < 128) ? (W3[k * 128 + n] - W3[(64 + k) * 128 + n])
                             : W3[(64 + k) * 128 + (n - 128)];
        }
    } else if (f < W5F) {             // W4 [128][128]
        int fx = f - W4F, kc = fx >> 3, nt = fx & 7;
        int k0 = kc * 32 + q * 8, n = nt * 16 + c;
#pragma unroll
        for (int j = 0; j < 8; ++j) v[j] = W4[(k0 + j) * 128 + n];
    } else if (f < W6F) {             // W5 [128][128]
        int fx = f - W5F, kc = fx >> 3, nt = fx & 7;
        int k0 = kc * 32 + q * 8, n = nt * 16 + c;
#pragma unroll
        for (int j = 0; j < 8; ++j) v[j] = W5[(k0 + j) * 128 + n];
    } else {                          // W6 [128][40] padded to 48
        int fx = f - W6F, kc = fx / 3, nt = fx % 3;
        int k0 = kc * 32 + q * 8, n = nt * 16 + c;
#pragma unroll
        for (int j = 0; j < 8; ++j)
            v[j] = (n < 40) ? W6[(k0 + j) * 40 + n] : 0.0f;
    }
    unsigned hs[8], ls[8];
#pragma unroll
    for (int j = 0; j < 8; ++j) {
        unsigned h = f2bf_rne_u(v[j]);
        float r = v[j] - bfu2f(h);
        hs[j] = h;
        ls[j] = f2bf_rne_u(r);
    }
    uint4 H, L;
    H.x = hs[0] | (hs[1] << 16); H.y = hs[2] | (hs[3] << 16);
    H.z = hs[4] | (hs[5] << 16); H.w = hs[6] | (hs[7] << 16);
    L.x = ls[0] | (ls[1] << 16); L.y = ls[2] | (ls[3] << 16);
    L.z = ls[4] | (ls[5] << 16); L.w = ls[6] | (ls[7] << 16);
    *(uint4*)(WH + (size_t)d * 8) = H;
    *(uint4*)(WL + (size_t)d * 8) = L;
}

// ---------------- K1: A1 = x@(W1t-W1b)+b1, B1 = x@W1b ----------------
__global__ __launch_bounds__(256) void k1_kernel(
    const float* __restrict__ x, const float* __restrict__ W1,
    const float* __restrict__ b1, float* __restrict__ A1, float* __restrict__ B1)
{
    int gid = blockIdx.x * 256 + threadIdx.x;
    int n = gid >> 6;
    int j = gid & 63;
    const float* xr = x + n * 16;
    float acc_a = b1[j];
    float acc_b = 0.0f;
#pragma unroll
    for (int k = 0; k < 16; ++k) {
        float xv = xr[k];
        float wt = W1[k * 64 + j];
        float wb = W1[(16 + k) * 64 + j];
        acc_a = fmaf(xv, wt - wb, acc_a);
        acc_b = fmaf(xv, wb, acc_b);
    }
    A1[n * 64 + j] = acc_a;
    B1[n * 64 + j] = acc_b;
}

// ---------------- K2 (MFMA): 64 rows/block; t=relu(A1+B1[col]) -> h=relu(t@W2+b2)
//                  -> A3 = h@(W3t-W3b)+b3, B3 = h@W3b (combined 256-col GEMM) ----
__global__ __launch_bounds__(256) void k2_kernel(
    const int* __restrict__ col,
    const float* __restrict__ A1, const float* __restrict__ B1,
    const unsigned short* __restrict__ WH, const unsigned short* __restrict__ WL,
    const float* __restrict__ b2, const float* __restrict__ b3,
    float* __restrict__ A3, float* __restrict__ B3)
{
    __shared__ __align__(16) float tF[8 * 512];   // 16 KB, frag-contig fp32
    __shared__ __align__(16) float hF[8 * 512];   // 16 KB
    const int t = threadIdx.x;
    const int i0 = blockIdx.x * 64;

    // phase A: t[row] = relu(A1[i>>4] + B1[col[i]]) -> tF frag layout
    {
        const int row = t & 63, part = t >> 6;
        int i = i0 + row;                 // tail reads valid (i < EE), stores guarded
        int nn = i >> 4;
        int ci = col[i];
        const float* ar = A1 + (size_t)nn * 64 + part * 16;
        const float* br = B1 + (size_t)ci * 64 + part * 16;
        int mt = row >> 4, m = row & 15, kc = part >> 1;
        float* base = tF + (mt * 2 + kc) * 512 + m * 8;
#pragma unroll
        for (int h = 0; h < 2; ++h) {
            int qq = (part & 1) * 2 + h;
            float4 a0 = *(const float4*)(ar + h * 8);
            float4 b0 = *(const float4*)(br + h * 8);
            float4 a1 = *(const float4*)(ar + h * 8 + 4);
            float4 b1v = *(const float4*)(br + h * 8 + 4);
            float4 r0, r1;
            r0.x = fmaxf(a0.x + b0.x, 0.0f); r0.y = fmaxf(a0.y + b0.y, 0.0f);
            r0.z = fmaxf(a0.z + b0.z, 0.0f); r0.w = fmaxf(a0.w + b0.w, 0.0f);
            r1.x = fmaxf(a1.x + b1v.x, 0.0f); r1.y = fmaxf(a1.y + b1v.y, 0.0f);
            r1.z = fmaxf(a1.z + b1v.z, 0.0f); r1.w = fmaxf(a1.w + b1v.w, 0.0f);
            *(float4*)(base + qq * 128) = r0;
            *(float4*)(base + qq * 128 + 4) = r1;
        }
    }
    __syncthreads();

    const int w = __builtin_amdgcn_readfirstlane(t >> 6);   // wave = m-tile
    const int lane = t & 63;

    // GEMM1: h-tile rows w*16..+15; acc1[nt=0..3]
    floatx4 acc1[4];
#pragma unroll
    for (int nt = 0; nt < 4; ++nt) acc1[nt] = (floatx4){0.f, 0.f, 0.f, 0.f};
#pragma unroll
    for (int kc = 0; kc < 2; ++kc) {
        const float* ap = tF + (w * 2 + kc) * 512 + lane * 8;
        bf16x8 ah, al;
        split8(*(const float4*)ap, *(const float4*)(ap + 4), ah, al);
#pragma unroll
        for (int nt = 0; nt < 4; ++nt) {
            size_t fb = (size_t)(W2F + kc * 4 + nt) * 512 + lane * 8;
            bf16x8 bh = __builtin_bit_cast(bf16x8, *(const uint4*)(WH + fb));
            bf16x8 bl = __builtin_bit_cast(bf16x8, *(const uint4*)(WL + fb));
            acc1[nt] = __builtin_amdgcn_mfma_f32_16x16x32_bf16(ah, bh, acc1[nt], 0, 0, 0);
            acc1[nt] = __builtin_amdgcn_mfma_f32_16x16x32_bf16(ah, bl, acc1[nt], 0, 0, 0);
            acc1[nt] = __builtin_amdgcn_mfma_f32_16x16x32_bf16(al, bh, acc1[nt], 0, 0, 0);
        }
    }
    // h = relu(acc1 + b2) -> hF frag layout (wave-local rows -> no barrier)
    {
        const int qq = lane >> 4, cc = lane & 15;
#pragma unroll
        for (int nt = 0; nt < 4; ++nt) {
            float bv = b2[nt * 16 + cc];
            int colIdx = nt * 16 + cc;
            int kc2 = colIdx >> 5, q2 = (colIdx >> 3) & 3, jj = cc & 7;
            float* dst = hF + (w * 2 + kc2) * 512 + q2 * 128 + jj;
#pragma unroll
            for (int r = 0; r < 4; ++r)
                dst[(qq * 4 + r) * 8] = fmaxf(acc1[nt][r] + bv, 0.0f);
        }
    }
    // GEMM2: [16 x 64] @ W3X[64 x 256]; acc2[nt=0..15]
    floatx4 acc2[16];
#pragma unroll
    for (int nt = 0; nt < 16; ++nt) acc2[nt] = (floatx4){0.f, 0.f, 0.f, 0.f};
#pragma unroll
    for (int kc = 0; kc < 2; ++kc) {
        const float* ap = hF + (w * 2 + kc) * 512 + lane * 8;
        bf16x8 ah, al;
        split8(*(const float4*)ap, *(const float4*)(ap + 4), ah, al);
#pragma unroll
        for (int nt = 0; nt < 16; ++nt) {
            size_t fb = (size_t)(W3F + kc * 16 + nt) * 512 + lane * 8;
            bf16x8 bh = __builtin_bit_cast(bf16x8, *(const uint4*)(WH + fb));
            bf16x8 bl = __builtin_bit_cast(bf16x8, *(const uint4*)(WL + fb));
            acc2[nt] = __builtin_amdgcn_mfma_f32_16x16x32_bf16(ah, bh, acc2[nt], 0, 0, 0);
            acc2[nt] = __builtin_amdgcn_mfma_f32_16x16x32_bf16(ah, bl, acc2[nt], 0, 0, 0);
            acc2[nt] = __builtin_amdgcn_mfma_f32_16x16x32_bf16(al, bh, acc2[nt], 0, 0, 0);
        }
    }
    // store: cols 0-127 -> A3 (+b3), 128-255 -> B3
    {
        const int qq = lane >> 4, cc = lane & 15;
#pragma unroll
        for (int nt = 0; nt < 16; ++nt) {
            int n = nt * 16 + cc;
            float bv = (n < 128) ? b3[n] : 0.0f;
#pragma unroll
            for (int r = 0; r < 4; ++r) {
                int i = i0 + w * 16 + qq * 4 + r;
                if (i < NN) {
                    float vv = acc2[nt][r];
                    if (n < 128) A3[(size_t)i * 128 + n] = vv + bv;
                    else         B3[(size_t)i * 128 + (n - 128)] = vv;
                }
            }
        }
    }
}

// ---------------- K3 (R4 version): MFMA edge-GEMM + in-register K-max ---------
__global__ __launch_bounds__(256) void k3_kernel(
    const int* __restrict__ col,
    const float* __restrict__ A3, const float* __restrict__ B3,
    const unsigned short* __restrict__ WH, const unsigned short* __restrict__ WL,
    const float* __restrict__ b4, float* __restrict__ g)
{
    __shared__ float sh_a[512];
    __shared__ __align__(16) unsigned short aHi[8192];
    __shared__ __align__(16) unsigned short aLo[8192];
    const int t = threadIdx.x;
    const int node0 = blockIdx.x * 4;
    const int e0 = node0 * KNB;
    const int row = t & 63;
    const int kcm = t >> 6;

    sh_a[t]       = A3[(size_t)node0 * 128 + t];
    sh_a[t + 256] = A3[(size_t)node0 * 128 + t + 256];
    __syncthreads();

    {
        const int c = col[e0 + row];
        const int mt = row >> 4, m = row & 15;
        const float* brow = B3 + (size_t)c * 128 + kcm * 32;
        const float* arow = sh_a + mt * 128 + kcm * 32;
        const int base = (mt * 4 + kcm) * 512 + m * 8;
#pragma unroll
        for (int q = 0; q < 4; ++q) {
            unsigned hs[8], ls[8];
#pragma unroll
            for (int i = 0; i < 8; i += 4) {
                float4 bv = *(const float4*)(brow + q * 8 + i);
                float4 av = *(const float4*)(arow + q * 8 + i);
                float vv[4];
                vv[0] = fmaxf(av.x + bv.x, 0.0f); vv[1] = fmaxf(av.y + bv.y, 0.0f);
                vv[2] = fmaxf(av.z + bv.z, 0.0f); vv[3] = fmaxf(av.w + bv.w, 0.0f);
#pragma unroll
                for (int u = 0; u < 4; ++u) {
                    unsigned h = f2bf_rne_u(vv[u]);
                    float r = vv[u] - bfu2f(h);
                    hs[i + u] = h;
                    ls[i + u] = f2bf_rne_u(r);
                }
            }
            uint4 H, L;
            H.x = hs[0] | (hs[1] << 16); H.y = hs[2] | (hs[3] << 16);
            H.z = hs[4] | (hs[5] << 16); H.w = hs[6] | (hs[7] << 16);
            L.x = ls[0] | (ls[1] << 16); L.y = ls[2] | (ls[3] << 16);
            L.z = ls[4] | (ls[5] << 16); L.w = ls[6] | (ls[7] << 16);
            *(uint4*)(aHi + base + q * 128) = H;
            *(uint4*)(aLo + base + q * 128) = L;
        }
    }
    __syncthreads();

    const int wv = t >> 6;
    const int lane = t & 63;
    const int ntb = wv * 2;
    floatx4 acc[4][2];
#pragma unroll
    for (int mt = 0; mt < 4; ++mt)
#pragma unroll
        for (int ntl = 0; ntl < 2; ++ntl)
            acc[mt][ntl] = (floatx4){0.0f, 0.0f, 0.0f, 0.0f};

    for (int kc = 0; kc < 4; ++kc) {
        bf16x8 bh[2], bl[2];
#pragma unroll
        for (int ntl = 0; ntl < 2; ++ntl) {
            int nt = ntb + ntl;
            bh[ntl] = __builtin_bit_cast(bf16x8,
                *(const uint4*)(WH + (size_t)((kc * 8 + nt) * 64 + lane) * 8));
            bl[ntl] = __builtin_bit_cast(bf16x8,
                *(const uint4*)(WL + (size_t)((kc * 8 + nt) * 64 + lane) * 8));
        }
        bf16x8 ah[4], al[4];
#pragma unroll
        for (int mt = 0; mt < 4; ++mt) {
            ah[mt] = __builtin_bit_cast(bf16x8,
                *(const uint4*)(aHi + (mt * 4 + kc) * 512 + lane * 8));
            al[mt] = __builtin_bit_cast(bf16x8,
                *(const uint4*)(aLo + (mt * 4 + kc) * 512 + lane * 8));
        }
#pragma unroll
        for (int mt = 0; mt < 4; ++mt)
#pragma unroll
            for (int ntl = 0; ntl < 2; ++ntl) {
                acc[mt][ntl] = __builtin_amdgcn_mfma_f32_16x16x32_bf16(
                    ah[mt], bh[ntl], acc[mt][ntl], 0, 0, 0);
                acc[mt][ntl] = __builtin_amdgcn_mfma_f32_16x16x32_bf16(
                    ah[mt], bl[ntl], acc[mt][ntl], 0, 0, 0);
                acc[mt][ntl] = __builtin_amdgcn_mfma_f32_16x16x32_bf16(
                    al[mt], bh[ntl], acc[mt][ntl], 0, 0, 0);
            }
    }

#pragma unroll
    for (int mt = 0; mt < 4; ++mt)
#pragma unroll
        for (int ntl = 0; ntl < 2; ++ntl) {
            floatx4 a = acc[mt][ntl];
            float mm = fmaxf(fmaxf(a[0], a[1]), fmaxf(a[2], a[3]));
            mm = fmaxf(mm, __shfl_xor(mm, 16));
            mm = fmaxf(mm, __shfl_xor(mm, 32));
            if (lane < 16) {
                int ccol = (ntb + ntl) * 16 + lane;
                g[(size_t)(node0 + mt) * 128 + ccol] =
                    fmaxf(mm + b4[ccol], 0.0f);
            }
        }
}

// ---------------- K4 (MFMA): 64 nodes/block; out = relu(g@W5+b5)@W6+b6 --------
__global__ __launch_bounds__(256) void k4_kernel(
    const float* __restrict__ g,
    const unsigned short* __restrict__ WH, const unsigned short* __restrict__ WL,
    const float* __restrict__ b5, const float* __restrict__ b6,
    float* __restrict__ out)
{
    __shared__ __align__(16) float gF[16 * 512];   // 32 KB, frag-contig fp32
    const int t = threadIdx.x;
    const int n0 = blockIdx.x * 64;

    // phase A: stage g rows into frag layout (clamp tail)
    {
        const int row = t & 63, part = t >> 6;    // part == kc
        int gn = n0 + row; if (gn >= NN) gn = NN - 1;
        const float* gr = g + (size_t)gn * 128 + part * 32;
        int mt = row >> 4, m = row & 15;
        float* base = gF + (mt * 4 + part) * 512 + m * 8;
#pragma unroll
        for (int qq = 0; qq < 4; ++qq) {
            *(float4*)(base + qq * 128)     = *(const float4*)(gr + qq * 8);
            *(float4*)(base + qq * 128 + 4) = *(const float4*)(gr + qq * 8 + 4);
        }
    }
    __syncthreads();

    const int w = __builtin_amdgcn_readfirstlane(t >> 6);
    const int lane = t & 63;

    // GEMM1: t1-tile rows w*16..+15; acc1[nt=0..7]
    floatx4 acc1[8];
#pragma unroll
    for (int nt = 0; nt < 8; ++nt) acc1[nt] = (floatx4){0.f, 0.f, 0.f, 0.f};
#pragma unroll
    for (int kc = 0; kc < 4; ++kc) {
        const float* ap = gF + (w * 4 + kc) * 512 + lane * 8;
        bf16x8 ah, al;
        split8(*(const float4*)ap, *(const float4*)(ap + 4), ah, al);
#pragma unroll
        for (int nt = 0; nt < 8; ++nt) {
            size_t fb = (size_t)(W5F + kc * 8 + nt) * 512 + lane * 8;
            bf16x8 bh = __builtin_bit_cast(bf16x8, *(const uint4*)(WH + fb));
            bf16x8 bl = __builtin_bit_cast(bf16x8, *(const uint4*)(WL + fb));
            acc1[nt] = __builtin_amdgcn_mfma_f32_16x16x32_bf16(ah, bh, acc1[nt], 0, 0, 0);
            acc1[nt] = __builtin_amdgcn_mfma_f32_16x16x32_bf16(ah, bl, acc1[nt], 0, 0, 0);
            acc1[nt] = __builtin_amdgcn_mfma_f32_16x16x32_bf16(al, bh, acc1[nt], 0, 0, 0);
        }
    }
    // t1 = relu(acc1 + b5) -> overwrite own frags (wave-local, reads done)
    {
        const int qq = lane >> 4, cc = lane & 15;
#pragma unroll
        for (int nt = 0; nt < 8; ++nt) {
            float bv = b5[nt * 16 + cc];
            int colIdx = nt * 16 + cc;
            int kc2 = colIdx >> 5, q2 = (colIdx >> 3) & 3, jj = cc & 7;
            float* dst = gF + (w * 4 + kc2) * 512 + q2 * 128 + jj;
#pragma unroll
            for (int r = 0; r < 4; ++r)
                dst[(qq * 4 + r) * 8] = fmaxf(acc1[nt][r] + bv, 0.0f);
        }
    }
    // GEMM2: [16 x 128] @ W6pad[128 x 48]; acc2[nt=0..2]
    floatx4 acc2[3];
#pragma unroll
    for (int nt = 0; nt < 3; ++nt) acc2[nt] = (floatx4){0.f, 0.f, 0.f, 0.f};
#pragma unroll
    for (int kc = 0; kc < 4; ++kc) {
        const float* ap = gF + (w * 4 + kc) * 512 + lane * 8;
        bf16x8 ah, al;
        split8(*(const float4*)ap, *(const float4*)(ap + 4), ah, al);
#pragma unroll
        for (int nt = 0; nt < 3; ++nt) {
            size_t fb = (size_t)(W6F + kc * 3 + nt) * 512 + lane * 8;
            bf16x8 bh = __builtin_bit_cast(bf16x8, *(const uint4*)(WH + fb));
            bf16x8 bl = __builtin_bit_cast(bf16x8, *(const uint4*)(WL + fb));
            acc2[nt] = __builtin_amdgcn_mfma_f32_16x16x32_bf16(ah, bh, acc2[nt], 0, 0, 0);
            acc2[nt] = __builtin_amdgcn_mfma_f32_16x16x32_bf16(ah, bl, acc2[nt], 0, 0, 0);
            acc2[nt] = __builtin_amdgcn_mfma_f32_16x16x32_bf16(al, bh, acc2[nt], 0, 0, 0);
        }
    }
    // store out (cols >= 40 are pad)
    {
        const int qq = lane >> 4, cc = lane & 15;
#pragma unroll
        for (int nt = 0; nt < 3; ++nt) {
            int n = nt * 16 + cc;
            if (n < 40) {
                float bv = b6[n];
#pragma unroll
                for (int r = 0; r < 4; ++r) {
                    int i = n0 + w * 16 + qq * 4 + r;
                    if (i < NN)
                        out[(size_t)i * 40 + n] = acc2[nt][r] + bv;
                }
            }
        }
    }
}

extern "C" void kernel_launch(void* const* d_in, const int* in_sizes, int n_in,
                              void* d_out, int out_size, void* d_ws, size_t ws_size,
                              hipStream_t stream)
{
    const float* x  = (const float*)d_in[0];
    const int* ei   = (const int*)d_in[1];
    const int* col  = ei + EE;
    const float* W1 = (const float*)d_in[2];
    const float* b1 = (const float*)d_in[3];
    const float* W2 = (const float*)d_in[4];
    const float* b2 = (const float*)d_in[5];
    const float* W3 = (const float*)d_in[6];
    const float* b3 = (const float*)d_in[7];
    const float* W4 = (const float*)d_in[8];
    const float* b4 = (const float*)d_in[9];
    const float* W5 = (const float*)d_in[10];
    const float* b5 = (const float*)d_in[11];
    const float* W6 = (const float*)d_in[12];
    const float* b6 = (const float*)d_in[13];
    float* out = (float*)d_out;

    float* A1 = (float*)d_ws;                    // [N,64]
    float* B1 = A1 + (size_t)NN * 64;            // [N,64]
    float* A3 = B1 + (size_t)NN * 64;            // [N,128]
    float* B3 = A3 + (size_t)NN * 128;           // [N,128]
    unsigned short* WH = (unsigned short*)(B3 + (size_t)NN * 128);  // [116*512]
    unsigned short* WL = WH + NFRAG * 512;
    float* g  = A1;                              // [N,128] reuses A1/B1 (dead after k2)

    kw_kernel<<<(NFRAG * 64 + 255) / 256, 256, 0, stream>>>(W2, W3, W4, W5, W6, WH, WL);
    k1_kernel<<<NN * 64 / 256, 256, 0, stream>>>(x, W1, b1, A1, B1);
    k2_kernel<<<(NN + 63) / 64, 256, 0, stream>>>(col, A1, B1, WH, WL, b2, b3, A3, B3);
    k3_kernel<<<NN / 4, 256, 0, stream>>>(col, A3, B3,
                                          WH + (size_t)W4F * 512, WL + (size_t)W4F * 512,
                                          b4, g);
    k4_kernel<<<(NN + 63) / 64, 256, 0, stream>>>(g, WH, WL, b5, b6, out);
}